// Round 14
// baseline (244.196 us; speedup 1.0000x reference)
//
#include <hip/hip_runtime.h>
#include <hip/hip_cooperative_groups.h>

namespace cg = cooperative_groups;

#define HH 256
#define WW 256
#define BB 4
#define HW (HH*WW)
#define N_ITER 20
#define EPSV 1e-8f

#define FUSE 4
#define NPH  5                   // 5 phases x 4 iters = 20
#define TILE 32
#define HALO (2*FUSE)            // 8
#define EXT  (TILE + 2*HALO)     // 48
#define EPAD 49                  // odd row stride in float4 cells
#define NTHR 768                 // 16 strips of 3 rows x 48 cols
#define RPS  3                   // rows per strip

__device__ __forceinline__ float ldz(const float* __restrict__ p, int y, int x) {
    if ((unsigned)y < HH && (unsigned)x < WW) return p[y*WW + x];
    return 0.0f;
}

__global__ __launch_bounds__(NTHR)
void tvl1_persist(const float* __restrict__ xin,
                  float* __restrict__ u,
                  float* __restrict__ p1, float* __restrict__ p2,
                  const float* __restrict__ lam, const float* __restrict__ tau,
                  const float* __restrict__ the) {
    cg::grid_group gridg = cg::this_grid();

    // All-b128 LDS (b64 empirically unsafe: R6/R10).
    // sp cell = (p1c0,p1c1,p2c0,p2c1); su cell = (u0,u1,0,0).
    __shared__ float4 su[EXT][EPAD];
    __shared__ float4 sp[EXT][EPAD];     // 2 * 48*49*16B = 75.3 KB

    const int tid = threadIdx.x;
    const int sx  = tid % EXT;               // column 0..47
    const int sy3 = (tid / EXT) * RPS;       // strip top row: 0,3,...,45
    const int b  = blockIdx.z;
    const int ox = blockIdx.x*TILE - HALO;
    const int oy = blockIdx.y*TILE - HALO;
    const int pb = b*2*HW;
    const float theta = the[0];
    const float tl = theta * lam[0];
    const float r = tau[0] / theta;

    const int gxx = ox + sx;
    const bool inx = ((unsigned)gxx < WW);

    float ru0[RPS], ru1[RPS], rp10[RPS], rp11[RPS], rp20[RPS], rp21[RPS];
    float rgx[RPS], rgy[RPS], rrc[RPS];
    bool updr[RPS];

    // Clamped window edges: taps of any upd pixel are in-bounds by
    // construction; clamped cells only feed dead (non-upd) computations.
    const int rT = (sy3 == 0) ? 0 : sy3 - 1;
    const int rB = (sy3 + RPS >= EXT) ? EXT-1 : sy3 + RPS;
    const int xm = (sx == 0) ? 0 : sx - 1;
    const int xp = (sx == EXT-1) ? EXT-1 : sx + 1;

    #pragma unroll
    for (int j = 0; j < RPS; ++j) {
        int ry = sy3 + j;
        bool img = inx && ((unsigned)(oy + ry) < HH);
        // update set: in-image (SAME-pad zeros stay zero) + stencil-readable.
        // No ring shrinking: stale ring-h values are never read by a pixel
        // that remains valid (1 ring per half-step, halo = 8 = #half-steps).
        updr[j] = img && (ry >= 1) && (ry < EXT-1) && (sx >= 1) && (sx < EXT-1);
    }

    // ---- phase-0 init: g from im1 via LDS window; u = p = 0 ----
    // Halo g computed locally is exact for rings >=1 (full 3x3 window in-tile,
    // im1 staged with image-bounds zeros); ring 0 never updates -> never used.
    {
        float im1r[RPS], im0r[RPS];
        #pragma unroll
        for (int j = 0; j < RPS; ++j) {
            int gyy = oy + sy3 + j;
            im1r[j] = ldz(xin + pb + HW, gyy, gxx);
            im0r[j] = ldz(xin + pb,      gyy, gxx);
            su[sy3 + j][sx] = make_float4(im1r[j], im0r[j], 0.f, 0.f);
        }
        __syncthreads();
        float4 Vm[RPS+2], Vc[RPS+2], Vp[RPS+2];   // V[i] = row sy3-1+i
        Vm[0] = su[rT][xm];     Vc[0] = su[rT][sx];   Vp[0] = su[rT][xp];
        Vm[1] = su[sy3  ][xm];                        Vp[1] = su[sy3  ][xp];
        Vm[2] = su[sy3+1][xm];                        Vp[2] = su[sy3+1][xp];
        Vm[3] = su[sy3+2][xm];                        Vp[3] = su[sy3+2][xp];
        Vm[4] = su[rB][xm];     Vc[4] = su[rB][sx];   Vp[4] = su[rB][xp];
        Vc[1] = make_float4(im1r[0], im0r[0], 0.f, 0.f);
        Vc[2] = make_float4(im1r[1], im0r[1], 0.f, 0.f);
        Vc[3] = make_float4(im1r[2], im0r[2], 0.f, 0.f);
        #pragma unroll
        for (int j = 0; j < RPS; ++j) {
            rgx[j] = (Vp[j].x-Vm[j].x) + 2.f*(Vp[j+1].x-Vm[j+1].x) + (Vp[j+2].x-Vm[j+2].x);
            rgy[j] = (Vm[j+2].x-Vm[j].x) + 2.f*(Vc[j+2].x-Vc[j].x) + (Vp[j+2].x-Vp[j].x);
            rrc[j] = im1r[j] - im0r[j];
            ru0[j]=0.f; ru1[j]=0.f;
            rp10[j]=0.f; rp11[j]=0.f; rp20[j]=0.f; rp21[j]=0.f;
        }
        __syncthreads();    // all windows read before su is repurposed
        #pragma unroll
        for (int j = 0; j < RPS; ++j) {
            su[sy3 + j][sx] = make_float4(0.f, 0.f, 0.f, 0.f);
            sp[sy3 + j][sx] = make_float4(0.f, 0.f, 0.f, 0.f);
        }
        __syncthreads();
    }

    for (int ph = 0; ph < NPH; ++ph) {
        const bool last = (ph == NPH-1);

        if (ph > 0) {
            // ---- stage u,p (g stays in regs); LDS gets neighbor-visible copies ----
            #pragma unroll
            for (int j = 0; j < RPS; ++j) {
                int ry = sy3 + j;
                int gyy = oy + ry;
                bool img = inx && ((unsigned)gyy < HH);
                float v0=0.f,v1=0.f,w0=0.f,w1=0.f,w2=0.f,w3=0.f;
                if (img) {
                    int gi = gyy*WW + gxx;
                    v0 = u[pb + gi];   v1 = u[pb + HW + gi];
                    w0 = p1[pb + gi];  w1 = p1[pb + HW + gi];
                    w2 = p2[pb + gi];  w3 = p2[pb + HW + gi];
                }
                ru0[j]=v0; ru1[j]=v1; rp10[j]=w0; rp11[j]=w1; rp20[j]=w2; rp21[j]=w3;
                su[ry][sx] = make_float4(v0, v1, 0.f, 0.f);
                sp[ry][sx] = make_float4(w0, w1, w2, w3);
            }
            __syncthreads();
        }

        #pragma unroll
        for (int it = 0; it < FUSE; ++it) {
            // ---- u half-step: p window from LDS (12 b128), pointwise from regs ----
            {
                float4 Wm[RPS+2], Wc[RPS+2], Wp[RPS+2];
                Wm[0] = sp[rT][xm];     Wc[0] = sp[rT][sx];   Wp[0] = sp[rT][xp];
                Wm[1] = sp[sy3  ][xm];                        Wp[1] = sp[sy3  ][xp];
                Wm[2] = sp[sy3+1][xm];                        Wp[2] = sp[sy3+1][xp];
                Wm[3] = sp[sy3+2][xm];                        Wp[3] = sp[sy3+2][xp];
                Wm[4] = sp[rB][xm];     Wc[4] = sp[rB][sx];   Wp[4] = sp[rB][xp];
                Wc[1] = make_float4(rp10[0], rp11[0], rp20[0], rp21[0]);
                Wc[2] = make_float4(rp10[1], rp11[1], rp20[1], rp21[1]);
                Wc[3] = make_float4(rp10[2], rp11[2], rp20[2], rp21[2]);
                #pragma unroll
                for (int j = 0; j < RPS; ++j) {
                    if (updr[j]) {
                        // SBX over p1 (.x,.y); SBY over p2 (.z,.w)
                        float x0 = (Wp[j].x-Wm[j].x) + 2.f*(Wp[j+1].x-Wm[j+1].x) + (Wp[j+2].x-Wm[j+2].x);
                        float x1 = (Wp[j].y-Wm[j].y) + 2.f*(Wp[j+1].y-Wm[j+1].y) + (Wp[j+2].y-Wm[j+2].y);
                        float y0 = (Wm[j+2].z-Wm[j].z) + 2.f*(Wc[j+2].z-Wc[j].z) + (Wp[j+2].z-Wp[j].z);
                        float y1 = (Wm[j+2].w-Wm[j].w) + 2.f*(Wc[j+2].w-Wc[j].w) + (Wp[j+2].w-Wp[j].w);

                        float g_x = rgx[j], g_y = rgy[j];
                        float ng  = g_x*g_x + g_y*g_y + EPSV;
                        float rho = rrc[j] + g_x*ru0[j] + g_y*ru1[j];
                        float th  = tl * ng;
                        float sgn = (rho > 0.f) ? 1.f : ((rho < 0.f) ? -1.f : 0.f);
                        float dd  = (fabsf(rho) < th) ? (rho / ng) : (tl * sgn);
                        ru0[j] = ru0[j] - dd*g_x + theta*(x0 + y0);
                        ru1[j] = ru1[j] - dd*g_y + theta*(x1 + y1);
                        su[sy3+j][sx] = make_float4(ru0[j], ru1[j], 0.f, 0.f);
                    }
                }
            }
            __syncthreads();

            if (last && it == FUSE-1) break;    // 20th p-update never feeds output

            // ---- p half-step: u window from LDS (12 b128), pointwise from regs ----
            {
                float4 Vm[RPS+2], Vc[RPS+2], Vp[RPS+2];
                Vm[0] = su[rT][xm];     Vc[0] = su[rT][sx];   Vp[0] = su[rT][xp];
                Vm[1] = su[sy3  ][xm];                        Vp[1] = su[sy3  ][xp];
                Vm[2] = su[sy3+1][xm];                        Vp[2] = su[sy3+1][xp];
                Vm[3] = su[sy3+2][xm];                        Vp[3] = su[sy3+2][xp];
                Vm[4] = su[rB][xm];     Vc[4] = su[rB][sx];   Vp[4] = su[rB][xp];
                Vc[1] = make_float4(ru0[0], ru1[0], 0.f, 0.f);
                Vc[2] = make_float4(ru0[1], ru1[1], 0.f, 0.f);
                Vc[3] = make_float4(ru0[2], ru1[2], 0.f, 0.f);
                #pragma unroll
                for (int j = 0; j < RPS; ++j) {
                    if (updr[j]) {
                        float g1x = (Vp[j].x-Vm[j].x) + 2.f*(Vp[j+1].x-Vm[j+1].x) + (Vp[j+2].x-Vm[j+2].x);
                        float g1y = (Vm[j+2].x-Vm[j].x) + 2.f*(Vc[j+2].x-Vc[j].x) + (Vp[j+2].x-Vp[j].x);
                        float g2x = (Vp[j].y-Vm[j].y) + 2.f*(Vp[j+1].y-Vm[j+1].y) + (Vp[j+2].y-Vm[j+2].y);
                        float g2y = (Vm[j+2].y-Vm[j].y) + 2.f*(Vc[j+2].y-Vc[j].y) + (Vp[j+2].y-Vp[j].y);
                        float inv1 = 1.f / (1.f + r*(fabsf(g1x) + fabsf(g1y)));
                        float inv2 = 1.f / (1.f + r*(fabsf(g2x) + fabsf(g2y)));
                        rp10[j] = (rp10[j] + r*g1x) * inv1;
                        rp11[j] = (rp11[j] + r*g1y) * inv1;
                        rp20[j] = (rp20[j] + r*g2x) * inv2;
                        rp21[j] = (rp21[j] + r*g2y) * inv2;
                        sp[sy3+j][sx] = make_float4(rp10[j], rp11[j], rp20[j], rp21[j]);
                    }
                }
            }
            __syncthreads();
        }

        // ---- write back interior straight from registers ----
        #pragma unroll
        for (int j = 0; j < RPS; ++j) {
            int ry = sy3 + j;
            if (updr[j] && ry >= HALO && ry < HALO+TILE && sx >= HALO && sx < HALO+TILE) {
                int go = (oy + ry)*WW + (ox + sx);
                u[pb + go]      = ru0[j];
                u[pb + HW + go] = ru1[j];
                if (!last) {
                    p1[pb + go]      = rp10[j];
                    p1[pb + HW + go] = rp11[j];
                    p2[pb + go]      = rp20[j];
                    p2[pb + HW + go] = rp21[j];
                }
            }
        }

        if (!last) gridg.sync();   // uniform across grid; fences + barrier
    }
}

extern "C" void kernel_launch(void* const* d_in, const int* in_sizes, int n_in,
                              void* d_out, int out_size, void* d_ws, size_t ws_size,
                              hipStream_t stream) {
    const float* xin = (const float*)d_in[0];
    const float* lam = (const float*)d_in[1];
    const float* tau = (const float*)d_in[2];
    const float* the = (const float*)d_in[3];
    float* u = (float*)d_out;              // u lives in d_out (B,2,H,W)

    float* ws = (float*)d_ws;
    float* p1 = ws;                        // B*2*HW
    float* p2 = ws + (size_t)BB*2*HW;      // B*2*HW

    dim3 blk(NTHR, 1, 1);
    dim3 grd(WW/TILE, HH/TILE, BB);        // 8 x 8 x 4 = 256 blocks = 1/CU
    void* args[] = { (void*)&xin, (void*)&u, (void*)&p1, (void*)&p2,
                     (void*)&lam, (void*)&tau, (void*)&the };
    hipLaunchCooperativeKernel(reinterpret_cast<void*>(tvl1_persist),
                               grd, blk, args, 0, stream);
}

// Round 15
// 83.757 us; speedup vs baseline: 2.9155x; 2.9155x over previous
//
#include <hip/hip_runtime.h>

#define HH 256
#define WW 256
#define BB 4
#define HW (HH*WW)
#define N_ITER 20
#define EPSV 1e-8f

#define FUSE 4
#define TILE 32
#define HALO (2*FUSE)            // 8
#define EXT  (TILE + 2*HALO)     // 48
#define EPAD 49                  // odd row stride in float4 cells
#define NTHR 768                 // 16 strips of 3 rows x 48 cols
#define RPS  3                   // rows per strip

__device__ __forceinline__ float ldz(const float* __restrict__ p, int y, int x) {
    if ((unsigned)y < HH && (unsigned)x < WW) return p[y*WW + x];
    return 0.0f;
}

template<int FIRST, int LAST>
__global__ __launch_bounds__(NTHR)
void tvl1_fused(const float* __restrict__ xin,
                float* __restrict__ u,
                float4* __restrict__ p4,      // (p1c0,p1c1,p2c0,p2c1) per px
                float4* __restrict__ g4,      // (gx, gy, rc, 0) per px
                const float* __restrict__ lam, const float* __restrict__ tau,
                const float* __restrict__ the) {
    // All-b128 LDS (b64 empirically unsafe: R6/R10).
    // sp cell = (p1c0,p1c1,p2c0,p2c1); su cell = (u0,u1,0,0).
    // Each thread owns a 3-row column strip: own-column cells in regs;
    // one 5-row x 3-col window (12 b128 reads) serves all 3 pixels per phase.
    __shared__ float4 su[EXT][EPAD];
    __shared__ float4 sp[EXT][EPAD];     // 2 * 48*49*16B = 75.3 KB

    const int tid = threadIdx.x;
    const int sx  = tid % EXT;               // column 0..47 (const divisor)
    const int sy3 = (tid / EXT) * RPS;       // strip top row: 0,3,...,45
    const int b  = blockIdx.z;
    const int ox = blockIdx.x*TILE - HALO;
    const int oy = blockIdx.y*TILE - HALO;
    const int pb = b*2*HW, cb = b*HW;
    const float theta = the[0];
    const float tl = theta * lam[0];
    const float r = tau[0] / theta;

    const int gxx = ox + sx;
    const bool inx = ((unsigned)gxx < WW);

    float ru0[RPS], ru1[RPS], rp10[RPS], rp11[RPS], rp20[RPS], rp21[RPS];
    float rgx[RPS], rgy[RPS], rrc[RPS];
    bool updr[RPS];

    // Clamped window edges: taps of any upd pixel are in-bounds by
    // construction; clamped cells only feed dead (non-upd) computations.
    const int rT = (sy3 == 0) ? 0 : sy3 - 1;
    const int rB = (sy3 + RPS >= EXT) ? EXT-1 : sy3 + RPS;
    const int xm = (sx == 0) ? 0 : sx - 1;
    const int xp = (sx == EXT-1) ? EXT-1 : sx + 1;

    #pragma unroll
    for (int j = 0; j < RPS; ++j) {
        int ry = sy3 + j;
        bool img = inx && ((unsigned)(oy + ry) < HH);
        // update set: in-image (SAME-pad zeros stay zero) + stencil-readable.
        // No ring shrinking: stale ring-h values are never read by a pixel
        // that remains valid (1 ring per half-step, halo = 8 = #half-steps).
        updr[j] = img && (ry >= 1) && (ry < EXT-1) && (sx >= 1) && (sx < EXT-1);
    }

    if (FIRST) {
        // ---- stage (im1, im0) into su; compute g in-LDS; u = p = 0 ----
        float im1r[RPS], im0r[RPS];
        #pragma unroll
        for (int j = 0; j < RPS; ++j) {
            int gyy = oy + sy3 + j;
            im1r[j] = ldz(xin + pb + HW, gyy, gxx);
            im0r[j] = ldz(xin + pb,      gyy, gxx);
            su[sy3 + j][sx] = make_float4(im1r[j], im0r[j], 0.f, 0.f);
        }
        __syncthreads();
        {
            float4 Vm[RPS+2], Vc[RPS+2], Vp[RPS+2];   // V[i] = row sy3-1+i
            Vm[0] = su[rT][xm];     Vc[0] = su[rT][sx];   Vp[0] = su[rT][xp];
            Vm[1] = su[sy3  ][xm];                        Vp[1] = su[sy3  ][xp];
            Vm[2] = su[sy3+1][xm];                        Vp[2] = su[sy3+1][xp];
            Vm[3] = su[sy3+2][xm];                        Vp[3] = su[sy3+2][xp];
            Vm[4] = su[rB][xm];     Vc[4] = su[rB][sx];   Vp[4] = su[rB][xp];
            Vc[1] = make_float4(im1r[0], im0r[0], 0.f, 0.f);
            Vc[2] = make_float4(im1r[1], im0r[1], 0.f, 0.f);
            Vc[3] = make_float4(im1r[2], im0r[2], 0.f, 0.f);
            #pragma unroll
            for (int j = 0; j < RPS; ++j) {
                // sobel of im1 (.x): SX has no center column, SY no middle row
                rgx[j] = (Vp[j].x-Vm[j].x) + 2.f*(Vp[j+1].x-Vm[j+1].x) + (Vp[j+2].x-Vm[j+2].x);
                rgy[j] = (Vm[j+2].x-Vm[j].x) + 2.f*(Vc[j+2].x-Vc[j].x) + (Vp[j+2].x-Vp[j].x);
                rrc[j] = im1r[j] - im0r[j];
                ru0[j]=0.f; ru1[j]=0.f;
                rp10[j]=0.f; rp11[j]=0.f; rp20[j]=0.f; rp21[j]=0.f;
                // persist g for dispatches 2..5 (interior cells exactly
                // partition the image across blocks)
                int ry = sy3 + j;
                if (ry >= HALO && ry < HALO+TILE && sx >= HALO && sx < HALO+TILE) {
                    int gi = (oy + ry)*WW + gxx;
                    g4[cb + gi] = make_float4(rgx[j], rgy[j], rrc[j], 0.f);
                }
            }
        }
        __syncthreads();    // all windows read before su is repurposed
        #pragma unroll
        for (int j = 0; j < RPS; ++j) {
            su[sy3 + j][sx] = make_float4(0.f, 0.f, 0.f, 0.f);
            sp[sy3 + j][sx] = make_float4(0.f, 0.f, 0.f, 0.f);
        }
        __syncthreads();
    } else {
        // ---- stage: 2 scalar + 2 b128 global loads per cell ----
        #pragma unroll
        for (int j = 0; j < RPS; ++j) {
            int ry = sy3 + j;
            int gyy = oy + ry;
            bool img = inx && ((unsigned)gyy < HH);
            float v0=0.f, v1=0.f;
            float4 P = make_float4(0.f,0.f,0.f,0.f);
            float4 G = make_float4(0.f,0.f,0.f,0.f);
            if (img) {
                int gi = gyy*WW + gxx;
                v0 = u[pb + gi];   v1 = u[pb + HW + gi];
                P  = p4[cb + gi];
                G  = g4[cb + gi];
            }
            ru0[j]=v0; ru1[j]=v1;
            rp10[j]=P.x; rp11[j]=P.y; rp20[j]=P.z; rp21[j]=P.w;
            rgx[j]=G.x; rgy[j]=G.y; rrc[j]=G.z;
            su[ry][sx] = make_float4(v0, v1, 0.f, 0.f);
            sp[ry][sx] = P;
        }
        __syncthreads();
    }

    #pragma unroll
    for (int it = 0; it < FUSE; ++it) {
        // ---- u half-step: p window from LDS (12 b128), pointwise from regs ----
        {
            float4 Wm[RPS+2], Wc[RPS+2], Wp[RPS+2];    // W[i] = row sy3-1+i
            Wm[0] = sp[rT][xm];     Wc[0] = sp[rT][sx];   Wp[0] = sp[rT][xp];
            Wm[1] = sp[sy3  ][xm];                        Wp[1] = sp[sy3  ][xp];
            Wm[2] = sp[sy3+1][xm];                        Wp[2] = sp[sy3+1][xp];
            Wm[3] = sp[sy3+2][xm];                        Wp[3] = sp[sy3+2][xp];
            Wm[4] = sp[rB][xm];     Wc[4] = sp[rB][sx];   Wp[4] = sp[rB][xp];
            Wc[1] = make_float4(rp10[0], rp11[0], rp20[0], rp21[0]);
            Wc[2] = make_float4(rp10[1], rp11[1], rp20[1], rp21[1]);
            Wc[3] = make_float4(rp10[2], rp11[2], rp20[2], rp21[2]);
            #pragma unroll
            for (int j = 0; j < RPS; ++j) {
                if (updr[j]) {
                    // SBX over p1 (.x,.y): no center column
                    float x0 = (Wp[j].x-Wm[j].x) + 2.f*(Wp[j+1].x-Wm[j+1].x) + (Wp[j+2].x-Wm[j+2].x);
                    float x1 = (Wp[j].y-Wm[j].y) + 2.f*(Wp[j+1].y-Wm[j+1].y) + (Wp[j+2].y-Wm[j+2].y);
                    // SBY over p2 (.z,.w): no middle row
                    float y0 = (Wm[j+2].z-Wm[j].z) + 2.f*(Wc[j+2].z-Wc[j].z) + (Wp[j+2].z-Wp[j].z);
                    float y1 = (Wm[j+2].w-Wm[j].w) + 2.f*(Wc[j+2].w-Wc[j].w) + (Wp[j+2].w-Wp[j].w);

                    float g_x = rgx[j], g_y = rgy[j];
                    float ng  = g_x*g_x + g_y*g_y + EPSV;
                    float rho = rrc[j] + g_x*ru0[j] + g_y*ru1[j];
                    float th  = tl * ng;
                    float sgn = (rho > 0.f) ? 1.f : ((rho < 0.f) ? -1.f : 0.f);
                    float dd  = (fabsf(rho) < th) ? (rho / ng) : (tl * sgn);
                    ru0[j] = ru0[j] - dd*g_x + theta*(x0 + y0);
                    ru1[j] = ru1[j] - dd*g_y + theta*(x1 + y1);
                    su[sy3+j][sx] = make_float4(ru0[j], ru1[j], 0.f, 0.f);
                }
            }
        }
        __syncthreads();

        if (LAST && it == FUSE-1) break;    // 20th p-update never feeds the output

        // ---- p half-step: u window from LDS (12 b128), pointwise from regs ----
        {
            float4 Vm[RPS+2], Vc[RPS+2], Vp[RPS+2];
            Vm[0] = su[rT][xm];     Vc[0] = su[rT][sx];   Vp[0] = su[rT][xp];
            Vm[1] = su[sy3  ][xm];                        Vp[1] = su[sy3  ][xp];
            Vm[2] = su[sy3+1][xm];                        Vp[2] = su[sy3+1][xp];
            Vm[3] = su[sy3+2][xm];                        Vp[3] = su[sy3+2][xp];
            Vm[4] = su[rB][xm];     Vc[4] = su[rB][sx];   Vp[4] = su[rB][xp];
            Vc[1] = make_float4(ru0[0], ru1[0], 0.f, 0.f);
            Vc[2] = make_float4(ru0[1], ru1[1], 0.f, 0.f);
            Vc[3] = make_float4(ru0[2], ru1[2], 0.f, 0.f);
            #pragma unroll
            for (int j = 0; j < RPS; ++j) {
                if (updr[j]) {
                    float g1x = (Vp[j].x-Vm[j].x) + 2.f*(Vp[j+1].x-Vm[j+1].x) + (Vp[j+2].x-Vm[j+2].x);
                    float g1y = (Vm[j+2].x-Vm[j].x) + 2.f*(Vc[j+2].x-Vc[j].x) + (Vp[j+2].x-Vp[j].x);
                    float g2x = (Vp[j].y-Vm[j].y) + 2.f*(Vp[j+1].y-Vm[j+1].y) + (Vp[j+2].y-Vm[j+2].y);
                    float g2y = (Vm[j+2].y-Vm[j].y) + 2.f*(Vc[j+2].y-Vc[j].y) + (Vp[j+2].y-Vp[j].y);
                    float inv1 = 1.f / (1.f + r*(fabsf(g1x) + fabsf(g1y)));
                    float inv2 = 1.f / (1.f + r*(fabsf(g2x) + fabsf(g2y)));
                    rp10[j] = (rp10[j] + r*g1x) * inv1;
                    rp11[j] = (rp11[j] + r*g1y) * inv1;
                    rp20[j] = (rp20[j] + r*g2x) * inv2;
                    rp21[j] = (rp21[j] + r*g2y) * inv2;
                    sp[sy3+j][sx] = make_float4(rp10[j], rp11[j], rp20[j], rp21[j]);
                }
            }
        }
        __syncthreads();
    }

    // ---- write back interior straight from registers ----
    #pragma unroll
    for (int j = 0; j < RPS; ++j) {
        int ry = sy3 + j;
        if (updr[j] && ry >= HALO && ry < HALO+TILE && sx >= HALO && sx < HALO+TILE) {
            int go = (oy + ry)*WW + (ox + sx);
            u[pb + go]      = ru0[j];
            u[pb + HW + go] = ru1[j];
            if (!LAST)
                p4[cb + go] = make_float4(rp10[j], rp11[j], rp20[j], rp21[j]);
        }
    }
}

extern "C" void kernel_launch(void* const* d_in, const int* in_sizes, int n_in,
                              void* d_out, int out_size, void* d_ws, size_t ws_size,
                              hipStream_t stream) {
    const float* xin = (const float*)d_in[0];
    const float* lam = (const float*)d_in[1];
    const float* tau = (const float*)d_in[2];
    const float* the = (const float*)d_in[3];
    float* u = (float*)d_out;              // u lives in d_out (B,2,H,W)

    // ws layout: packed float4 planes (16B-aligned by construction)
    float4* p4 = (float4*)d_ws;                    // BB*HW cells (4 MB)
    float4* g4 = p4 + (size_t)BB*HW;               // BB*HW cells (4 MB)

    dim3 blk(NTHR, 1, 1);
    dim3 grd(WW/TILE, HH/TILE, BB);        // 8 x 8 x 4 = 256 blocks = 1/CU
    // 5 dispatches: init merged into kernel 1 (computes g in-LDS, starts
    // from u=p=0); packed p4/g4 cut staging to 4 loads / 3 stores per cell.
    tvl1_fused<1,0><<<grd, blk, 0, stream>>>(xin, u, p4, g4, lam, tau, the);
    tvl1_fused<0,0><<<grd, blk, 0, stream>>>(xin, u, p4, g4, lam, tau, the);
    tvl1_fused<0,0><<<grd, blk, 0, stream>>>(xin, u, p4, g4, lam, tau, the);
    tvl1_fused<0,0><<<grd, blk, 0, stream>>>(xin, u, p4, g4, lam, tau, the);
    tvl1_fused<0,1><<<grd, blk, 0, stream>>>(xin, u, p4, g4, lam, tau, the);
}